// Round 1
// baseline (105.768 us; speedup 1.0000x reference)
//
#include <hip/hip_runtime.h>
#include <stdint.h>

#define NUM_PIDS 20000
#define NCOPIES 16
#define TBL_ELEMS (NUM_PIDS * NCOPIES)
#define FIX_SHIFT 20
#define FIX_SCALE 1048576.0f   // 2^20
#define CNT_SHIFT 44
#define FIX_MASK ((1ULL << CNT_SHIFT) - 1)

// ws layout: [ u64 tbl[NCOPIES][NUM_PIDS] | float acc[2] ]
// acc[0] = sum of per-pid means, acc[1] = K (present pid count)

__global__ void zero_ws_kernel(unsigned long long* __restrict__ tbl,
                               float* __restrict__ acc) {
    int i = blockIdx.x * blockDim.x + threadIdx.x;
    int stride = gridDim.x * blockDim.x;
    for (; i < TBL_ELEMS; i += stride) tbl[i] = 0ULL;
    if (blockIdx.x == 0 && threadIdx.x < 2) acc[threadIdx.x] = 0.0f;
}

__global__ void __launch_bounds__(256) accum_kernel(
        const float4* __restrict__ pred,
        const float4* __restrict__ track,
        const int* __restrict__ pid,
        const int* __restrict__ recon,
        unsigned long long* __restrict__ tbl,
        int n) {
    // privatized copy per block (mod NCOPIES) to spread atomic contention
    unsigned long long* mytbl = tbl + (int)(blockIdx.x & (NCOPIES - 1)) * NUM_PIDS;
    int i = blockIdx.x * blockDim.x + threadIdx.x;
    int stride = gridDim.x * blockDim.x;
    for (; i < n; i += stride) {
        int p = pid[i];
        int r = recon[i];
        if ((r > 0) && (p > 0)) {   // pid 0 and invalid hits excluded by reference
            float4 a0 = pred[2 * i],  a1 = pred[2 * i + 1];
            float4 b0 = track[2 * i], b1 = track[2 * i + 1];
            float d0 = a0.x - b0.x, d1 = a0.y - b0.y;
            float d2 = a0.z - b0.z, d3 = a0.w - b0.w;
            float d4 = a1.x - b1.x, d5 = a1.y - b1.y;
            float d6 = a1.z - b1.z, d7 = a1.w - b1.w;
            float mse = d0*d0 + d1*d1 + d2*d2 + d3*d3
                      + d4*d4 + d5*d5 + d6*d6 + d7*d7;
            // packed: count in bits [44..63], fixed-point (2^-20) mse sum in [0..43]
            unsigned long long fx = (unsigned long long)(mse * FIX_SCALE + 0.5f);
            unsigned long long packed = (1ULL << CNT_SHIFT) | fx;
            atomicAdd(&mytbl[p], packed);
        }
    }
}

__global__ void __launch_bounds__(256) reduce_kernel(
        const unsigned long long* __restrict__ tbl,
        float* __restrict__ acc) {
    int p = blockIdx.x * blockDim.x + threadIdx.x;
    float mean = 0.0f, pres = 0.0f;
    if (p >= 1 && p < NUM_PIDS) {
        unsigned long long s = 0ULL;
        #pragma unroll
        for (int c = 0; c < NCOPIES; ++c) s += tbl[c * NUM_PIDS + p];
        unsigned int cnt = (unsigned int)(s >> CNT_SHIFT);
        if (cnt > 0) {
            mean = (float)((double)(s & FIX_MASK) * (1.0 / 1048576.0)
                           / (double)cnt);
            pres = 1.0f;
        }
    }
    // wave64 reduce
    #pragma unroll
    for (int off = 32; off > 0; off >>= 1) {
        mean += __shfl_down(mean, off);
        pres += __shfl_down(pres, off);
    }
    __shared__ float smean[4], spres[4];
    int wave = threadIdx.x >> 6;
    int lane = threadIdx.x & 63;
    if (lane == 0) { smean[wave] = mean; spres[wave] = pres; }
    __syncthreads();
    if (threadIdx.x == 0) {
        float m = smean[0] + smean[1] + smean[2] + smean[3];
        float k = spres[0] + spres[1] + spres[2] + spres[3];
        atomicAdd(&acc[0], m);
        atomicAdd(&acc[1], k);
    }
}

__global__ void final_kernel(const float* __restrict__ acc,
                             float* __restrict__ out) {
    if (threadIdx.x == 0 && blockIdx.x == 0) {
        float K = acc[1];
        out[0] = (K > 0.0f) ? (100.0f * acc[0] / K) : 0.0f;
    }
}

extern "C" void kernel_launch(void* const* d_in, const int* in_sizes, int n_in,
                              void* d_out, int out_size, void* d_ws, size_t ws_size,
                              hipStream_t stream) {
    // setup_inputs order: W(0) beta(1) H(2) pred(3) Y(4) particle_id(5)
    //                     track_params(6) reconstructable(7)
    const float* pred  = (const float*)d_in[3];
    const int*   pid   = (const int*)d_in[5];
    const float* track = (const float*)d_in[6];
    const int*   recon = (const int*)d_in[7];
    int n = in_sizes[5];   // N hits

    unsigned long long* tbl = (unsigned long long*)d_ws;
    float* acc = (float*)((char*)d_ws + (size_t)TBL_ELEMS * sizeof(unsigned long long));

    zero_ws_kernel<<<256, 256, 0, stream>>>(tbl, acc);
    accum_kernel<<<2048, 256, 0, stream>>>((const float4*)pred, (const float4*)track,
                                           pid, recon, tbl, n);
    reduce_kernel<<<(NUM_PIDS + 255) / 256, 256, 0, stream>>>(tbl, acc);
    final_kernel<<<1, 64, 0, stream>>>(acc, (float*)d_out);
}